// Round 1
// 648.084 us; speedup vs baseline: 1.1183x; 1.1183x over previous
//
#include <hip/hip_runtime.h>

// Fused ConvTranspose3d(3->16, k3, s2, p1) * 0.5 -> AvgPool(2) -> +bias
// == VALID 2x2x2 conv, stride 1: x(4,3,128,128,128) -> out(4,16,127,127,127)
//
// R3 (from R2 @ ~724us total, conv_main not in rocprof top-5 => <328us):
//   - all 16 oc per thread (acc=64 VGPR): och grid dim removed -> grid
//     halved, every x byte loaded once instead of twice
//   - ow0 = (g<31 ? 4g : 123) remap: lane 31's outputs 123..126 are all
//     valid (123 written twice with identical values) -> every lane does
//     one dwordx4 store per oc, NO masking, NO divergence. Row bases are
//     only 4B-aligned (OS=127), so loads/stores go through memcpy to let
//     the compiler emit unaligned-capable dwordx4.
//   - e_off = ow0+4 is always <=127: clamp logic gone
//   - XCD swizzle with od innermost: consecutive blocks on an XCD share
//     a full d-plane (3ic x 64KB) in the per-XCD L2
//   - launch_bounds(256,3): allocator cap 168 VGPR (no spill risk);
//     expected actual ~110 -> 4 waves/SIMD at runtime

#define NB 4
#define IC 3
#define OC 16
#define XS 128              // input spatial
#define OS 127              // output spatial
#define OS3 (127 * 127 * 127)
#define OHB 16              // oh blocks of 8 rows (16*8=128, last row masked)
#define NBLK (NB * OS * OHB)       // 4*127*16 = 8128 (divisible by 8 XCDs)

// ---- prep: fold 3x3x3 weight -> fw[3][16][8] (tap = a*4+b*2+c), bias fb[16]
__global__ void prep_kernel(const float* __restrict__ W,   // (ic, oc, 3,3,3)
                            const float* __restrict__ CB,  // (16,)
                            const float* __restrict__ EB,  // (16,)
                            float* __restrict__ ws) {
    int t = threadIdx.x;
    if (t < IC * OC * 8) {
        int ic  = t >> 7;
        int oc  = (t >> 3) & 15;
        int abc = t & 7;
        int a = (abc >> 2) & 1, b = (abc >> 1) & 1, c = abc & 1;
        int kdlo = a ? 0 : 1, kdhi = a ? 0 : 2;
        int khlo = b ? 0 : 1, khhi = b ? 0 : 2;
        int kwlo = c ? 0 : 1, kwhi = c ? 0 : 2;
        const float* wp = W + (ic * OC + oc) * 27;
        float s = 0.f;
        for (int kd = kdlo; kd <= kdhi; ++kd)
            for (int kh = khlo; kh <= khhi; ++kh)
                for (int kw = kwlo; kw <= kwhi; ++kw)
                    s += wp[kd * 9 + kh * 3 + kw];
        ws[t] = s * 0.0625f;
    }
    if (t < OC) ws[IC * OC * 8 + t] = CB[t] * 0.5f + EB[t];
}

// unaligned-tolerant 16B load/store (row bases are only 4B-aligned)
__device__ __forceinline__ float4 ld4u(const float* p) {
    float4 v;
    __builtin_memcpy(&v, p, 16);
    return v;
}
__device__ __forceinline__ void st4u(float* p, float4 v) {
    __builtin_memcpy(p, &v, 16);
}

// c=0 tap: acc += q * s
__device__ __forceinline__ float4 fc0(const float4 q, const float s, float4 a) {
    a.x = __builtin_fmaf(q.x, s, a.x);
    a.y = __builtin_fmaf(q.y, s, a.y);
    a.z = __builtin_fmaf(q.z, s, a.z);
    a.w = __builtin_fmaf(q.w, s, a.w);
    return a;
}
// c=1 tap: acc += shift(q, e) * s   (shifted window: q.y q.z q.w e)
__device__ __forceinline__ float4 fc1(const float4 q, const float e,
                                      const float s, float4 a) {
    a.x = __builtin_fmaf(q.y, s, a.x);
    a.y = __builtin_fmaf(q.z, s, a.y);
    a.z = __builtin_fmaf(q.w, s, a.z);
    a.w = __builtin_fmaf(e,   s, a.w);
    return a;
}

__global__ __launch_bounds__(256, 3)
void conv_main(const float* __restrict__ X,
               const float* __restrict__ FW,   // ws: fw[384] then fb[16]
               float* __restrict__ OUT) {
    // XCD-contiguous swizzle; od varies fastest within an XCD chunk so
    // consecutive blocks share the od+1 d-plane in the per-XCD L2.
    int B    = blockIdx.x;
    int work = (B & 7) * (NBLK / 8) + (B >> 3);
    int od   = work % OS;
    int w2   = work / OS;           // 0..63
    int ohb  = w2 & 15;
    int n    = w2 >> 4;

    int t   = threadIdx.x;
    int ohl = t >> 5;               // 0..7
    int g   = t & 31;               // ow group
    int ow0 = (g < 31) ? (g << 2) : 123;   // lane31: window 123..127
    int oh  = (ohb << 3) + ohl;     // 0..127
    bool valid = (oh < OS);
    int ohc = valid ? oh : (OS - 1);       // clamp loads for masked row

    const float* fw = FW;                  // block-uniform -> s_load
    const float* fb = FW + IC * OC * 8;

    float4 acc[OC];
#pragma unroll
    for (int oc = 0; oc < OC; ++oc) {
        float bv = fb[oc];
        acc[oc] = make_float4(bv, bv, bv, bv);
    }

#pragma unroll
    for (int ic = 0; ic < IC; ++ic) {
        const float* xb = X + (((size_t)(n * IC + ic) * XS + od) * XS + ohc) * XS;
        float4 q[2][2];
        float  e[2][2];
#pragma unroll
        for (int a = 0; a < 2; ++a)
#pragma unroll
            for (int b = 0; b < 2; ++b) {
                const float* r = xb + (a * XS + b) * XS;
                q[a][b] = ld4u(r + ow0);       // lanes 0..30 are 16B aligned
                e[a][b] = r[ow0 + 4];          // max index 127: always valid
            }
        const float* wi = fw + ic * OC * 8;
#pragma unroll
        for (int oc = 0; oc < OC; ++oc) {
            const float* w = wi + oc * 8;      // uniform -> SGPRs
            float4 a4 = acc[oc];
            a4 = fc0(q[0][0],          w[0], a4);
            a4 = fc1(q[0][0], e[0][0], w[1], a4);
            a4 = fc0(q[0][1],          w[2], a4);
            a4 = fc1(q[0][1], e[0][1], w[3], a4);
            a4 = fc0(q[1][0],          w[4], a4);
            a4 = fc1(q[1][0], e[1][0], w[5], a4);
            a4 = fc0(q[1][1],          w[6], a4);
            a4 = fc1(q[1][1], e[1][1], w[7], a4);
            acc[oc] = a4;
        }
    }

    if (valid) {
        size_t obase = (size_t)n * OC * OS3
                     + ((size_t)od * OS + oh) * OS + ow0;
#pragma unroll
        for (int oc = 0; oc < OC; ++oc)
            st4u(OUT + obase + (size_t)oc * OS3, acc[oc]);  // full dwordx4,
                                                            // no mask/diverge
    }
}

extern "C" void kernel_launch(void* const* d_in, const int* in_sizes, int n_in,
                              void* d_out, int out_size, void* d_ws, size_t ws_size,
                              hipStream_t stream) {
    const float* X  = (const float*)d_in[0];   // (4,3,128,128,128)
    const float* W  = (const float*)d_in[1];   // (3,16,3,3,3)
    const float* CB = (const float*)d_in[2];   // (16,)
    const float* EB = (const float*)d_in[3];   // (16,1,1,1) flat 16
    float* OUT = (float*)d_out;                // (4,16,127,127,127)
    float* ws  = (float*)d_ws;                 // 384 fw + 16 fb = 1600 B

    prep_kernel<<<1, 384, 0, stream>>>(W, CB, EB, ws);
    conv_main<<<NBLK, 256, 0, stream>>>(X, ws, OUT);
}